// Round 3
// baseline (1003.822 us; speedup 1.0000x reference)
//
#include <hip/hip_runtime.h>
#include <hip/hip_bf16.h>

#define NN 10000
#define NE 320000
#define F_NODE 128
#define F_EDGE 64
#define HID 128
#define LAT 64

using bf16 = __hip_bfloat16;

// Runtime-dtype load: isbf selects bf16 vs f32 storage. Wave-uniform flag.
static __device__ __forceinline__ float ldf(const void* p, long i, int isbf) {
    if (isbf) return __bfloat162float(((const bf16*)p)[i]);
    return ((const float*)p)[i];
}

// ---------------- dtype detectors ----------------
// flags[0]=nf, flags[1]=ef, flags[2..13]=Wn1,bn1,We1,be1,Wm1,bm1,Wn2,bn2,We2,be2,Wm2,bm2
//   (1 = bf16 storage, 0 = f32 storage)
// flags[14]=src int64?, flags[15]=dst int64?  (1 = int64 words)
__global__ void k_detect(const void* nf, const void* ef,
                         const void* w0, const void* w1, const void* w2, const void* w3,
                         const void* w4, const void* w5, const void* w6, const void* w7,
                         const void* w8, const void* w9, const void* w10, const void* w11,
                         const int* srcp, const int* dstp, int* __restrict__ flags) {
    const void* ps[14] = {nf, ef, w0, w1, w2, w3, w4, w5, w6, w7, w8, w9, w10, w11};
    const int lens[14] = {NN * F_NODE, NE * F_EDGE,
                          16384, 128, 8192, 128, 16384, 128,
                          8192, 64, 4096, 64, 4096, 64};
    __shared__ int cntr;
    if (threadIdx.x == 0) cntr = 0;
    __syncthreads();
    int b = blockIdx.x;
    if (b < 14) {
        // f32 storage: even ushorts are low mantissa halves -> exponent field
        // ~uniform random (~72% outside [90,160]). bf16 storage: sane exponents.
        const unsigned short* raw = (const unsigned short*)ps[b];
        int S = lens[b] / 2; if (S > 2048) S = 2048;
        int c = 0;
        for (int i = threadIdx.x; i < S; i += 256) {
            unsigned short u = raw[2 * i];
            int e = (u >> 7) & 0xFF;
            if (e < 90 || e > 160) c++;
        }
        atomicAdd(&cntr, c);
        __syncthreads();
        if (threadIdx.x == 0) flags[b] = (10 * cntr > 3 * S) ? 0 : 1;
    } else {
        // int64 storage: odd words are high halves of small nonneg ints -> 0.
        const int* raw = (b == 14) ? srcp : dstp;
        int S = 2048;
        int c = 0;
        for (int i = threadIdx.x; i < S; i += 256) {
            if (raw[2 * i + 1] == 0) c++;
        }
        atomicAdd(&cntr, c);
        __syncthreads();
        if (threadIdx.x == 0) flags[b] = (2 * cntr > S) ? 1 : 0;
    }
}

// ---------------- weight/bias normalization to f32 ----------------
__global__ void k_convert_w(const void* w0, const void* w1, const void* w2, const void* w3,
                            const void* w4, const void* w5, const void* w6, const void* w7,
                            const void* w8, const void* w9, const void* w10, const void* w11,
                            const int* __restrict__ flags, float* __restrict__ wf) {
    const int WLEN[12] = {16384, 128, 8192, 128, 16384, 128, 8192, 64, 4096, 64, 4096, 64};
    const int WOFF[12] = {0, 16384, 16512, 24704, 24832, 41216, 41344, 49536, 49600, 53696, 53760, 57856};
    const void* ps[12] = {w0, w1, w2, w3, w4, w5, w6, w7, w8, w9, w10, w11};
    int t = blockIdx.x >> 6;
    int i = (blockIdx.x & 63) * 256 + threadIdx.x;
    if (i < WLEN[t]) wf[WOFF[t] + i] = ldf(ps[t], i, flags[2 + t]);
}

// ---------------- CSR build ----------------

__global__ void k_count(const int* __restrict__ dstp, const int* __restrict__ flags,
                        int* __restrict__ cnt) {
    int e = blockIdx.x * 256 + threadIdx.x;
    int w = flags[15];
    if (e < NE) atomicAdd(&cnt[dstp[(long)e << w]], 1);
}

__global__ void k_scan(const int* __restrict__ cnt, int* __restrict__ row_start) {
    __shared__ int buf[1024];
    __shared__ int carry;
    if (threadIdx.x == 0) carry = 0;
    __syncthreads();
    for (int base = 0; base < NN; base += 1024) {
        int i = base + threadIdx.x;
        int v = (i < NN) ? cnt[i] : 0;
        buf[threadIdx.x] = v;
        __syncthreads();
        for (int off = 1; off < 1024; off <<= 1) {
            int t = (threadIdx.x >= off) ? buf[threadIdx.x - off] : 0;
            __syncthreads();
            buf[threadIdx.x] += t;
            __syncthreads();
        }
        int excl = carry + buf[threadIdx.x] - v;
        if (i < NN) row_start[i] = excl;
        __syncthreads();
        if (threadIdx.x == 1023) carry += buf[1023];
        __syncthreads();
    }
    if (threadIdx.x == 0) row_start[NN] = carry;
}

__global__ void k_fill(const int* __restrict__ srcp, const int* __restrict__ dstp,
                       const int* __restrict__ flags,
                       const int* __restrict__ row_start, int* __restrict__ fill,
                       int2* __restrict__ epack) {
    int e = blockIdx.x * 256 + threadIdx.x;
    int ws_ = flags[14], wd = flags[15];
    if (e < NE) {
        int d = dstp[(long)e << wd];
        int s = srcp[(long)e << ws_];
        int pos = row_start[d] + atomicAdd(&fill[d], 1);
        epack[pos] = make_int2(e, s);
    }
}

// ---------------- Layer 1 ----------------
// h1[n] = relu( [(Sx/deg)@Wn1 + (Se/deg)@We1 + bn1 + be1] @ Wm1 + bm1 ),  0 if deg==0
__global__ void k_layer1(const void* __restrict__ nf, const void* __restrict__ ef,
                         const int* __restrict__ flags,
                         const int* __restrict__ row_start, const int* __restrict__ cnt,
                         const int2* __restrict__ epack,
                         const float* __restrict__ Wn1, const float* __restrict__ bn1,
                         const float* __restrict__ We1, const float* __restrict__ be1,
                         const float* __restrict__ Wm1, const float* __restrict__ bm1,
                         float* __restrict__ h1, float* __restrict__ bvec) {
    int n = blockIdx.x;
    int t = threadIdx.x;                       // 128 threads
    __shared__ float a_s[F_NODE], b_s[F_EDGE], t_s[HID];

    int fn = flags[0], fe = flags[1];
    int start = row_start[n], deg = cnt[n];
    float accx = 0.f, acce = 0.f;
    for (int i = 0; i < deg; i++) {
        int2 p = epack[start + i];
        accx += ldf(nf, (long)p.y * F_NODE + t, fn);
        if (t < F_EDGE) acce += ldf(ef, (long)p.x * F_EDGE + t, fe);
    }
    float inv = (deg > 0) ? (1.f / (float)deg) : 0.f;
    a_s[t] = accx * inv;
    if (t < F_EDGE) { b_s[t] = acce * inv; bvec[n * F_EDGE + t] = acce * inv; }
    __syncthreads();

    float acc = bn1[t] + be1[t];
    for (int k = 0; k < F_NODE; k++) acc += a_s[k] * Wn1[k * HID + t];
    for (int k = 0; k < F_EDGE; k++) acc += b_s[k] * We1[k * HID + t];
    t_s[t] = acc;
    __syncthreads();

    float o = bm1[t];
    for (int k = 0; k < HID; k++) o += t_s[k] * Wm1[k * HID + t];
    if (deg == 0) o = 0.f;
    o = fmaxf(o, 0.f);
    h1[n * HID + t] = o;
}

// ---------------- Layer 2 ----------------
__global__ void k_layer2(const float* __restrict__ h1, const float* __restrict__ bvec,
                         const int* __restrict__ row_start, const int* __restrict__ cnt,
                         const int2* __restrict__ epack,
                         const float* __restrict__ Wn2, const float* __restrict__ bn2,
                         const float* __restrict__ We2, const float* __restrict__ be2,
                         const float* __restrict__ Wm2, const float* __restrict__ bm2,
                         float* __restrict__ z, float* __restrict__ zout) {
    int n = blockIdx.x;
    int t = threadIdx.x;                       // 128 threads
    __shared__ float a_s[HID], b_s[F_EDGE], t_s[LAT];

    int start = row_start[n], deg = cnt[n];
    float accx = 0.f;
    for (int i = 0; i < deg; i++) {
        int2 p = epack[start + i];
        accx += h1[p.y * HID + t];
    }
    float inv = (deg > 0) ? (1.f / (float)deg) : 0.f;
    a_s[t] = accx * inv;
    if (t < F_EDGE) b_s[t] = bvec[n * F_EDGE + t];
    __syncthreads();

    if (t < LAT) {
        float acc = bn2[t] + be2[t];
        for (int k = 0; k < HID; k++) acc += a_s[k] * Wn2[k * LAT + t];
        for (int k = 0; k < F_EDGE; k++) acc += b_s[k] * We2[k * LAT + t];
        t_s[t] = acc;
    }
    __syncthreads();

    if (t < LAT) {
        float o = bm2[t];
        for (int k = 0; k < LAT; k++) o += t_s[k] * Wm2[k * LAT + t];
        if (deg == 0) o = 0.f;
        z[n * LAT + t] = o;
        zout[n * LAT + t] = o;            // f32 output
    }
}

// ---------------- adj = sigmoid(z @ z^T), f32 out ----------------
__global__ __launch_bounds__(256) void k_adj(const float* __restrict__ z,
                                             float* __restrict__ out) {
    __shared__ float As[64][65];
    __shared__ float Bs[64][65];
    int tx = threadIdx.x & 15;
    int ty = threadIdx.x >> 4;
    int r0 = blockIdx.y * 64;
    int c0 = blockIdx.x * 64;

    for (int i = threadIdx.x; i < 64 * 64; i += 256) {
        int row = i >> 6, k = i & 63;
        int gr = r0 + row;
        int gc = c0 + row;
        As[row][k] = (gr < NN) ? z[gr * LAT + k] : 0.f;
        Bs[row][k] = (gc < NN) ? z[gc * LAT + k] : 0.f;
    }
    __syncthreads();

    float acc[4][4] = {};
    for (int k = 0; k < 64; k++) {
        float a[4], b[4];
#pragma unroll
        for (int i = 0; i < 4; i++) a[i] = As[ty * 4 + i][k];
#pragma unroll
        for (int j = 0; j < 4; j++) b[j] = Bs[tx * 4 + j][k];
#pragma unroll
        for (int i = 0; i < 4; i++)
#pragma unroll
            for (int j = 0; j < 4; j++) acc[i][j] += a[i] * b[j];
    }

    int gcb = c0 + tx * 4;
    bool cok = (gcb + 3 < NN);   // NN % 4 == 0 -> group fully valid or fully invalid
#pragma unroll
    for (int i = 0; i < 4; i++) {
        int gr = r0 + ty * 4 + i;
        if (gr < NN && cok) {
            float4 pk;
            pk.x = 1.f / (1.f + __expf(-acc[i][0]));
            pk.y = 1.f / (1.f + __expf(-acc[i][1]));
            pk.z = 1.f / (1.f + __expf(-acc[i][2]));
            pk.w = 1.f / (1.f + __expf(-acc[i][3]));
            *(float4*)(out + (size_t)gr * NN + gcb) = pk;
        }
    }
}

// ---------------- launch ----------------

extern "C" void kernel_launch(void* const* d_in, const int* in_sizes, int n_in,
                              void* d_out, int out_size, void* d_ws, size_t ws_size,
                              hipStream_t stream) {
    const void* nf  = d_in[0];
    const void* ef  = d_in[1];
    const int*  src = (const int*)d_in[2];
    const int*  dst = (const int*)d_in[3];
    const void* W[12];
    for (int i = 0; i < 12; i++) W[i] = d_in[4 + i];

    char* ws = (char*)d_ws;
    size_t off = 0;
    auto alloc = [&](size_t bytes) -> void* {
        void* p = ws + off;
        off = (off + bytes + 255) & ~(size_t)255;
        return p;
    };
    int*   flags     = (int*)alloc(16 * sizeof(int));
    float* wf        = (float*)alloc(57920 * sizeof(float));
    int*   cnt       = (int*)alloc(NN * sizeof(int));
    int*   fill      = (int*)alloc(NN * sizeof(int));
    int*   row_start = (int*)alloc((NN + 1) * sizeof(int));
    int2*  epack     = (int2*)alloc((size_t)NE * sizeof(int2));
    float* bvec      = (float*)alloc((size_t)NN * F_EDGE * sizeof(float));
    float* h1        = (float*)alloc((size_t)NN * HID * sizeof(float));
    float* zf        = (float*)alloc((size_t)NN * LAT * sizeof(float));

    hipMemsetAsync(cnt, 0, NN * sizeof(int), stream);
    hipMemsetAsync(fill, 0, NN * sizeof(int), stream);

    k_detect<<<16, 256, 0, stream>>>(nf, ef,
        W[0], W[1], W[2], W[3], W[4], W[5], W[6], W[7], W[8], W[9], W[10], W[11],
        src, dst, flags);
    k_convert_w<<<12 * 64, 256, 0, stream>>>(
        W[0], W[1], W[2], W[3], W[4], W[5], W[6], W[7], W[8], W[9], W[10], W[11],
        flags, wf);

    k_count<<<(NE + 255) / 256, 256, 0, stream>>>(dst, flags, cnt);
    k_scan<<<1, 1024, 0, stream>>>(cnt, row_start);
    k_fill<<<(NE + 255) / 256, 256, 0, stream>>>(src, dst, flags, row_start, fill, epack);

    const float* Wn1 = wf + 0,     *bn1 = wf + 16384;
    const float* We1 = wf + 16512, *be1 = wf + 24704;
    const float* Wm1 = wf + 24832, *bm1 = wf + 41216;
    const float* Wn2 = wf + 41344, *bn2 = wf + 49536;
    const float* We2 = wf + 49600, *be2 = wf + 53696;
    const float* Wm2 = wf + 53760, *bm2 = wf + 57856;

    k_layer1<<<NN, 128, 0, stream>>>(nf, ef, flags, row_start, cnt, epack,
                                     Wn1, bn1, We1, be1, Wm1, bm1, h1, bvec);
    k_layer2<<<NN, 128, 0, stream>>>(h1, bvec, row_start, cnt, epack,
                                     Wn2, bn2, We2, be2, Wm2, bm2,
                                     zf, (float*)d_out);

    dim3 g((NN + 63) / 64, (NN + 63) / 64);
    k_adj<<<g, 256, 0, stream>>>(zf, (float*)d_out + (size_t)NN * LAT);
}